// Round 4
// baseline (139.607 us; speedup 1.0000x reference)
//
#include <hip/hip_runtime.h>

// Species-routed expert Linear as a bucketed grouped GEMM.
//   out[a] = rho[a] @ W[sym[a]] + b[sym[a]]   (NTA=65536, K=N=512, 4 species)
// R4: same tiling as R3 (BM=64 x BN=512, 8 waves) but the barrier no longer
//     drains vmcnt: raw s_barrier + lgkmcnt(0) only, depth-2 register
//     prefetch of the A-stage (HBM latency covered by ~2 K-steps), all 8
//     B-fragments front-loaded per K-step, XOR-swizzled A-LDS (0-conflict
//     both sides). Memset dispatch folded into pack_w.

#define NTA   65536
#define DIM_O 512
#define NMAXD 512
#define NSPE  4
#define BM    64
#define BK    64

typedef __attribute__((ext_vector_type(4))) float  f32x4;
typedef __attribute__((ext_vector_type(8))) short  bf16x8;
typedef __attribute__((ext_vector_type(4))) short  bf16x4;

__device__ __forceinline__ short f2bf(float f) {
    unsigned u = __builtin_bit_cast(unsigned, f);
    u += 0x7FFFu + ((u >> 16) & 1u);
    return (short)(u >> 16);
}

// LDS-visibility barrier that does NOT drain vmcnt (keeps A-prefetch in flight)
__device__ __forceinline__ void bar_lds() {
    asm volatile("s_waitcnt lgkmcnt(0)" ::: "memory");
    __builtin_amdgcn_s_barrier();
    __builtin_amdgcn_sched_barrier(0);
}

__global__ void build_lists_kernel(const int* __restrict__ sym,
                                   int* __restrict__ counts,
                                   int* __restrict__ lists) {
    int i = blockIdx.x * 256 + threadIdx.x;
    int s = sym[i];
    int lane = threadIdx.x & 63;
    #pragma unroll
    for (int spe = 0; spe < NSPE; ++spe) {
        unsigned long long m = __ballot(s == spe);
        if (m == 0ull) continue;
        int leader = __ffsll(m) - 1;
        int base = 0;
        if (lane == leader) base = atomicAdd(&counts[spe], __popcll(m));
        base = __shfl(base, leader);
        if (s == spe) {
            int pos = __popcll(m & ((1ull << lane) - 1ull));
            lists[spe * NTA + base + pos] = i;
        }
    }
}

// Pack W[s][k][n] (fp32) -> bf16 MFMA-B fragment layout. Also zeroes counts
// (this kernel is launched BEFORE build_lists on the same stream).
__global__ void pack_w_kernel(const float* __restrict__ W, short* __restrict__ Wp,
                              int* __restrict__ counts) {
    if (blockIdx.x == 0 && threadIdx.x < NSPE) counts[threadIdx.x] = 0;
    int idx = blockIdx.x * 256 + threadIdx.x;
    int j  = idx & 7;
    int l  = (idx >> 3) & 63;
    int nb = (idx >> 9) & 31;
    int kb = (idx >> 14) & 15;
    int s  = idx >> 18;
    int k = kb * 32 + (l >> 4) * 8 + j;
    int n = nb * 16 + (l & 15);
    Wp[idx] = f2bf(W[((size_t)s * DIM_O + k) * NMAXD + n]);
}

// LDS A layout: 16B slot = chunk*64 + (row ^ ((chunk&3)<<1)); chunk = k-floats
// [8c, 8c+8). XOR on row bits 1-2 breaks the 4-way staging-write conflict
// while keeping the (measured 0-conflict) read pattern conflict-free.
__global__ __launch_bounds__(512, 2)
void gemm_kernel(const float* __restrict__ rho,
                 const short* __restrict__ Wp,
                 const float* __restrict__ bias,
                 const int*  __restrict__ counts,
                 const int*  __restrict__ lists,
                 float* __restrict__ out)
{
    const int s   = blockIdx.x & 3;
    const int mb  = blockIdx.x >> 2;
    const int cnt = counts[s];
    const int row0 = mb * BM;
    if (row0 >= cnt) return;
    int rows_here = cnt - row0; if (rows_here > BM) rows_here = BM;

    __shared__ int aidx[BM];
    __shared__ __align__(16) short Abuf[2][8 * 64 * 8];  // 2 x 8 KB

    const int tid  = threadIdx.x;
    const int lane = tid & 63;
    const int w    = tid >> 6;            // wave 0..7 owns cols [w*64, w*64+64)
    const int lrow = lane & 15;
    const int lgr  = lane >> 4;

    if (tid < BM)
        aidx[tid] = lists[s * NTA + row0 + ((tid < rows_here) ? tid : 0)];
    __syncthreads();

    // merged staging: thread t -> row t>>3, 8 consecutive lanes read 128 B
    // contiguous of one row (requests merge in the TA)
    const int srow  = tid >> 3;
    const int scol8 = tid & 7;
    const float* gsrc = rho + (size_t)aidx[srow] * DIM_O + scol8 * 4;
    const int c0    = scol8 >> 1;
    const int roww  = srow ^ ((c0 & 3) << 1);       // write-side XOR swizzle
    const int dswz0 = ((c0    ) * 64 + roww) * 8 + (scol8 & 1) * 4;
    const int dswz1 = ((c0 + 4) * 64 + roww) * 8 + (scol8 & 1) * 4;

    const short* wbase = Wp + ((size_t)s * 512 + w * 4) * 512 + lane * 8;

    f32x4 acc[4][4];
    #pragma unroll
    for (int m = 0; m < 4; ++m)
        #pragma unroll
        for (int n = 0; n < 4; ++n) acc[m][n] = (f32x4)0.0f;

    f32x4 pre[3][2];   // depth-2 rotating A-prefetch (indices static after unroll)

    #define ISSUE(slot, step)                                            \
        { pre[slot][0] = *(const f32x4*)(gsrc + (step) * BK);            \
          pre[slot][1] = *(const f32x4*)(gsrc + (step) * BK + 32); }
    #define WRITEA(slot, b)                                              \
        { bf16x4 va, vb;                                                 \
          _Pragma("unroll")                                              \
          for (int q = 0; q < 4; ++q) {                                  \
              va[q] = f2bf(pre[slot][0][q]);                             \
              vb[q] = f2bf(pre[slot][1][q]);                             \
          }                                                              \
          *(bf16x4*)&Abuf[b][dswz0] = va;                                \
          *(bf16x4*)&Abuf[b][dswz1] = vb; }

    // prologue: stage step 0, get steps 1 and 2 in flight
    ISSUE(0, 0);
    ISSUE(1, 1);
    WRITEA(0, 0);          // waits (counted) on step-0 loads only
    ISSUE(2, 2);
    bar_lds();

    #pragma unroll
    for (int kt = 0; kt < 8; ++kt) {
        const int buf = kt & 1;
        // front-load this step's 8 B fragments (L2-resident Wp)
        bf16x8 bfr[2][4];
        #pragma unroll
        for (int ks = 0; ks < 2; ++ks)
            #pragma unroll
            for (int nf = 0; nf < 4; ++nf)
                bfr[ks][nf] = *(const bf16x8*)
                    (wbase + (size_t)((kt * 2 + ks) * 32 + nf) * 512);
        // keep the A-prefetch pipeline 2 steps deep
        if (kt + 3 < 8) ISSUE((kt + 3) % 3, kt + 3);

        #pragma unroll
        for (int ks = 0; ks < 2; ++ks) {
            #pragma unroll
            for (int mf = 0; mf < 4; ++mf) {
                const int c = ks * 4 + lgr;
                const int r = (mf * 16 + lrow) ^ ((c & 3) << 1);
                const bf16x8 afrag = *(const bf16x8*)&Abuf[buf][(c * 64 + r) * 8];
                #pragma unroll
                for (int nf = 0; nf < 4; ++nf)
                    acc[mf][nf] = __builtin_amdgcn_mfma_f32_16x16x32_bf16(
                        afrag, bfr[ks][nf], acc[mf][nf], 0, 0, 0);
            }
        }
        if (kt < 7) {
            WRITEA((kt + 1) % 3, buf ^ 1);   // counted vmcnt, never drains to 0
            bar_lds();
        }
    }
    #undef ISSUE
    #undef WRITEA

    // epilogue: bias + per-row store (16 lanes write 64 B contiguous per row)
    float bv[4];
    #pragma unroll
    for (int nf = 0; nf < 4; ++nf)
        bv[nf] = bias[s * NMAXD + w * 64 + nf * 16 + lrow];
    #pragma unroll
    for (int mf = 0; mf < 4; ++mf) {
        #pragma unroll
        for (int q = 0; q < 4; ++q) {
            const int r = mf * 16 + lgr * 4 + q;
            if (r < rows_here) {
                float* orow = out + (size_t)aidx[r] * NMAXD + w * 64 + lrow;
                #pragma unroll
                for (int nf = 0; nf < 4; ++nf)
                    orow[nf * 16] = acc[mf][nf][q] + bv[nf];
            }
        }
    }
}

extern "C" void kernel_launch(void* const* d_in, const int* in_sizes, int n_in,
                              void* d_out, int out_size, void* d_ws, size_t ws_size,
                              hipStream_t stream) {
    const float* rho = (const float*)d_in[0];
    const float* W   = (const float*)d_in[1];
    const float* b   = (const float*)d_in[2];
    const int*   sym = (const int*)d_in[3];
    float* out = (float*)d_out;

    int*   counts = (int*)d_ws;
    int*   lists  = (int*)((char*)d_ws + 1024);
    short* Wp     = (short*)((char*)d_ws + 1024 + (size_t)NSPE * NTA * 4);

    pack_w_kernel<<<(NSPE * DIM_O * NMAXD) / 256, 256, 0, stream>>>(W, Wp, counts);
    build_lists_kernel<<<NTA / 256, 256, 0, stream>>>(sym, counts, lists);
    gemm_kernel<<<NSPE * (NTA / BM), 512, 0, stream>>>(rho, Wp, b, counts, lists, out);
}